// Round 13
// baseline (23.334 us; speedup 1.0000x reference)
//
#include <hip/hip_runtime.h>

#define UU 128          // coarse sample count per ray
#define HH 32           // hidden width
#define WPB 4           // waves per block
#define NN 32           // sigma interpolation nodes per ray (32-lane half-wave)

#define NLOG2E_F  (-1.44269504088896f)
#define TWOLOG2E_F  2.88539008177793f
#define LN2_F       0.693147180559945f
#define FLTMAX_I  0x7F7FFFFF   // bits of FLT_MAX (positive -> int-min == float-min)

__device__ __forceinline__ float fexp2(float x){ return __builtin_amdgcn_exp2f(x); }
__device__ __forceinline__ float flog2(float x){ return __builtin_amdgcn_logf(x); }
__device__ __forceinline__ float frcp (float x){ return __builtin_amdgcn_rcpf(x); }
template<int L>
__device__ __forceinline__ float readlaneNf(float x){
  return __int_as_float(__builtin_amdgcn_readlane(__float_as_int(x), L));
}

template<int CTRL, int RMASK>
__device__ __forceinline__ float dppmovf(float x){
  return __int_as_float(__builtin_amdgcn_update_dpp(
      0, __float_as_int(x), CTRL, RMASK, 0xF, true));
}
template<int CTRL, int RMASK>
__device__ __forceinline__ int dppmovi(int x){
  return __builtin_amdgcn_update_dpp(0, x, CTRL, RMASK, 0xF, true);
}
__device__ __forceinline__ int imax2(int a, int b){ return a > b ? a : b; }

// 32-lane SEGMENTED inclusive scans (two independent segments per wave)
__device__ __forceinline__ float seg32_scan_add(float v){
  v += dppmovf<0x111, 0xF>(v);
  v += dppmovf<0x112, 0xF>(v);
  v += dppmovf<0x114, 0xF>(v);
  v += dppmovf<0x118, 0xF>(v);
  v += dppmovf<0x142, 0xA>(v);
  return v;
}
__device__ __forceinline__ int seg32_scan_max(int v){
  v = imax2(v, dppmovi<0x111, 0xF>(v));
  v = imax2(v, dppmovi<0x112, 0xF>(v));
  v = imax2(v, dppmovi<0x114, 0xF>(v));
  v = imax2(v, dppmovi<0x118, 0xF>(v));
  v = imax2(v, dppmovi<0x142, 0xA>(v));
  return v;
}
// whole-wave shifts by 1 lane (cross 16-lane rows); vacated lanes get 0.
__device__ __forceinline__ int wave_shr1_i(int x){
  return __builtin_amdgcn_update_dpp(0, x, 0x138, 0xF, 0xF, true);
}
__device__ __forceinline__ float wave_shr1_f(float x){
  return __int_as_float(__builtin_amdgcn_update_dpp(
      0, __float_as_int(x), 0x138, 0xF, 0xF, true));
}
__device__ __forceinline__ float wave_shl1_f(float x){
  return __int_as_float(__builtin_amdgcn_update_dpp(
      0, __float_as_int(x), 0x130, 0xF, 0xF, true));
}

// Soft fence: same-wave DS ops execute in order on the LDS pipe, so
// write->read visibility within a wave needs only a compiler barrier.
#define LDS_SOFT() do { \
  asm volatile("" ::: "memory"); \
  __builtin_amdgcn_wave_barrier(); \
} while (0)

// softplus(x) = max(x,0) + ln2*log2(1 + 2^(-log2e*|x|))
__device__ __forceinline__ float softplus_f(float x){
  float e = fexp2(NLOG2E_F * __builtin_fabsf(x));
  return __builtin_fmaxf(x, 0.0f) + LN2_F * flog2(1.0f + e);
}

// Catmull-Rom via precomputed per-cell coefficients C[i] = (s1, a1, a2, a3)
__device__ __forceinline__ float interp_sigmaC(const float4* C, float z,
                                               float z0, float invh){
  float t = __builtin_fmaxf((z - z0) * invh, 0.0f);
  int i = (int)t;
  i = (i < NN - 2) ? i : (NN - 2);
  float f = t - (float)i;
  float4 c = C[i];
  float p = __builtin_fmaf(__builtin_fmaf(__builtin_fmaf(c.w, f, c.z), f, c.y), f, c.x);
  return __builtin_fmaxf(p, 0.0f);
}

__global__ __launch_bounds__(256) void nerf_transmittance_kernel(
    const float* __restrict__ rays_o, const float* __restrict__ rays_d,
    const float* __restrict__ nearp, const float* __restrict__ farp,
    const float* __restrict__ noise, const float* __restrict__ W1,
    const float* __restrict__ b1, const float* __restrict__ W2,
    const float* __restrict__ b2, float* __restrict__ out, int nrays) {
  __shared__ __align__(16) float2 scg [WPB][2][HH];   // per-ray {c2,g2}
  __shared__ __align__(16) float4 scf [WPB][2][NN];   // cell coeffs [0..30]
  __shared__ __align__(16) float2 szc [WPB][2][UU];   // (zc_k, cdf_k)
  __shared__ __align__(16) int    smk [WPB][2][UU];   // P1-P4: scatter-max; P4-P5: firstnz

  const int tid  = threadIdx.x;
  const int wave = tid >> 6;
  const int lane = tid & 63;
  const int half = lane >> 5;          // which ray of the pair
  const int li   = lane & 31;          // lane within the 32-lane segment
  const int base = (blockIdx.x * WPB + wave) * 2;   // wave-uniform
  const int rA = (base < nrays) ? base : (nrays - 1);
  const int rB = (base + 1 < nrays) ? (base + 1) : (nrays - 1);
  const bool isB = (half != 0);

  // uniform scalar loads for both rays, per-lane select
  const float ox = isB ? rays_o[3*rB+0] : rays_o[3*rA+0];
  const float oy = isB ? rays_o[3*rB+1] : rays_o[3*rA+1];
  const float oz = isB ? rays_o[3*rB+2] : rays_o[3*rA+2];
  const float dx = isB ? rays_d[3*rB+0] : rays_d[3*rA+0];
  const float dy = isB ? rays_d[3*rB+1] : rays_d[3*rA+1];
  const float dz = isB ? rays_d[3*rB+2] : rays_d[3*rA+2];
  const float nv = isB ? nearp[rB] : nearp[rA];
  const float fv = isB ? farp[rB]  : farp[rA];
  const float sd   = (fv - nv) * (1.0f / UU);
  const float step = (fv - nv) * (1.0f / (UU - 1));

  // W2/b2 uniform: bacc = b2 + sum(w2); n2w2 = -2*w2 (SGPRs)
  float n2w2[HH];
  float bacc = b2[0];
  #pragma unroll
  for (int j = 0; j < HH; ++j) {
    float w2 = W2[j];
    bacc += w2;
    n2w2[j] = -2.0f * w2;
  }

  float2* cgh = &scg[wave][half][0];
  float4* cfh = &scf[wave][half][0];
  float2* zct = &szc[wave][half][0];
  int*    mk  = &smk[wave][half][0];

  // ---- P1: zero scatter-max array; per-ray affine fold (unit j = li) ----
  *(int4*)&mk[4*li] = make_int4(0, 0, 0, 0);
  {
    float wx = W1[li], wy = W1[HH + li], wz = W1[2*HH + li];
    float g = dx*wx + dy*wy + dz*wz;
    float c = ox*wx + oy*wy + oz*wz + b1[li];
    cgh[li] = make_float2(TWOLOG2E_F * c, TWOLOG2E_F * g);
  }
  LDS_SOFT();

  // ---- P2: node MLP (lane li -> node li); build cell coeff table ----
  const float z0   = nv - 0.5f * sd;
  const float span = (fv - nv) + sd;
  const float invh = (float)(NN - 1) * frcp(span);
  const float h    = span * (1.0f / (NN - 1));
  {
    float zn = __builtin_fmaf((float)li, h, z0);
    float acc = bacc;
    #pragma unroll
    for (int j = 0; j < HH; ++j) {
      const float2 c = cgh[j];                // 2-addr broadcast read
      float q = __builtin_fmaf(c.y, zn, c.x); // 2log2e * pre
      float e = fexp2(q);
      float rr = frcp(1.0f + e);              // tanh = 1 - 2r
      acc = __builtin_fmaf(n2w2[j], rr, acc);
    }
    float v = softplus_f(acc);

    // neighbor exchange via wave-wide DPP shifts + edge cndmask
    float s0 = wave_shr1_f(v);   // v_{i-1}; lane li==0 got other-segment/0
    s0 = (li == 0) ? v : s0;
    float s2 = wave_shl1_f(v);   // v_{i+1}; li==31 wrong but cell guarded
    float s3 = wave_shl1_f(s2);  // v_{i+2}; li>=30 wrong
    s3 = (li >= 30) ? s2 : s3;   // cell 30: s3 = v_31 (edge duplication)
    if (li < NN - 1) {
      float a1 = 0.5f * (s2 - s0);
      float a3 = __builtin_fmaf(1.5f, v - s2, 0.5f * (s3 - s0));
      float a2 = __builtin_fmaf(-2.5f, v, s0) + __builtin_fmaf(-0.5f, s3, 2.0f * s2);
      cfh[li] = make_float4(v, a1, a2, a3);
    }
  }
  LDS_SOFT();

  // ---- P3: coarse z/sigma, segmented scan, telescoped cdf, i* scatter ----
  const int rcur = isB ? rB : rA;
  const size_t nb = (size_t)rcur * UU;
  float4 n4 = *(const float4*)&noise[nb + 4*li];
  int nxi = 4*li + 4; nxi = (nxi < UU - 1) ? nxi : (UU - 1);
  float n5 = noise[nb + nxi];
  float nn_[5] = {n4.x, n4.y, n4.z, n4.w, n5};

  float zl[4], dl[4], sig[4];
  #pragma unroll
  for (int c = 0; c < 4; ++c) {
    zl[c] = __builtin_fmaf(step, (float)(4*li + c), nv) + (nn_[c] - 0.5f) * sd;
    dl[c] = step + (nn_[c+1] - nn_[c]) * sd;
    sig[c] = interp_sigmaC(cfh, zl[c], z0, invh);
  }
  if (li == 31) dl[3] = sd;   // sample 127's delta

  float a0 = dl[0]*sig[0], a1 = dl[1]*sig[1], a2 = dl[2]*sig[2], a3 = dl[3]*sig[3];
  float t0 = a0, t1 = t0 + a1, t2 = t1 + a2, t3 = t2 + a3;
  float incl = seg32_scan_add(t3);
  float excl = incl - t3;
  float Ti[4];
  Ti[0] = fexp2(NLOG2E_F * (excl + t0));
  Ti[1] = fexp2(NLOG2E_F * (excl + t1));
  Ti[2] = fexp2(NLOG2E_F * (excl + t2));
  Ti[3] = fexp2(NLOG2E_F * (excl + t3));

  float T1x  = isB ? readlaneNf<32>(Ti[0]) : readlaneNf<0>(Ti[0]);   // Tincl(0)
  float T126 = isB ? readlaneNf<63>(Ti[2]) : readlaneNf<31>(Ti[2]);  // Tincl(126)
  float itot = frcp(T1x - T126 + 126.0f * 1e-5f);

  float cdfv[4];
  #pragma unroll
  for (int c = 0; c < 4; ++c)
    cdfv[c] = (T1x - Ti[c] + (float)(4*li + c) * 1e-5f) * itot;

  *(float4*)&zct[4*li]     = make_float4(zl[0], cdfv[0], zl[1], cdfv[1]);
  *(float4*)&zct[4*li + 2] = make_float4(zl[2], cdfv[2], zl[3], cdfv[3]);

  #pragma unroll
  for (int c = 0; c < 4; ++c) {
    int k = 4*li + c;
    int is = (int)__builtin_ceilf(__builtin_fmaf(cdfv[c], 128.0f, -0.5f));
    if (k < 127 && is < 128) atomicMax(&mk[is], k);
  }
  LDS_SOFT();

  // ---- P4: below via segmented prefix-max; sample; rank; firstnz scatter ----
  int4 m4 = *(int4*)&mk[4*li];
  LDS_SOFT();  // reads of mk done (same-wave order); buffer now reused as firstnz
  *(int4*)&mk[4*li] = make_int4(FLTMAX_I, FLTMAX_I, FLTMAX_I, FLTMAX_I);

  int M3 = imax2(imax2(m4.x, m4.y), imax2(m4.z, m4.w));
  int incm = seg32_scan_max(M3);
  int exm = wave_shr1_i(incm);
  exm = (li == 0) ? 0 : exm;
  int bcv[4];
  bcv[0] = imax2(exm, m4.x);
  bcv[1] = imax2(bcv[0], m4.y);
  bcv[2] = imax2(bcv[1], m4.z);
  bcv[3] = imax2(bcv[2], m4.w);

  float nzv[4], sgn2[4], zrv[4];
  #pragma unroll
  for (int c = 0; c < 4; ++c) {
    float u = ((float)(4*li + c) + 0.5f) * (1.0f / UU);
    int b = bcv[c];                       // max{k: cdf_k <= u}, in [0,125]
    float2 p0 = zct[b];
    float2 p1 = zct[b + 1];
    float p2x = zct[b + 2].x;
    float den = p1.y - p0.y;
    if (den < 1e-5f) den = 1.0f;
    float t = (u - p0.y) * frcp(den);
    float bb = 0.5f * (p0.x + p1.x);
    float ba = 0.5f * (p1.x + p2x);
    float z = __builtin_fmaf(t, ba - bb, bb);
    nzv[c] = z;
    sgn2[c] = interp_sigmaC(cfh, z, z0, invh);
    bool up = (p1.x <= z);
    int rj = b + 1 + (up ? 1 : 0);            // rank of nz in zc, [1,127]
    zrv[c] = up ? p2x : p1.x;                 // zc[rank] from registers
    atomicMin(&mk[rj], __float_as_int(z));    // positive floats: int min ok
  }
  LDS_SOFT();

  // ---- P5: analytic merged-successor deltas, fused transmittance sum ----
  // succ(zc_i) = min(zc_{i+1}, firstnz[i+1]);  succ(nz_j) = min(nz_{j+1}, zc[r_j])
  int4 f4 = *(int4*)&mk[4*li];
  float nzn3 = __shfl_down(nzv[0], 1);                 // nz_{j+1} for c=3
  float zcn3 = __shfl_down(zl[0], 1);                  // zc_{i+1} for c=3
  int   fnn3 = __shfl_down(f4.x, 1);                   // firstnz[i+1] for c=3
  const bool lastl = (li == 31);

  float local = 0.0f;
  // zc side
  local += sig[0] * (__builtin_fminf(zl[1], __int_as_float(f4.y)) - zl[0]);
  local += sig[1] * (__builtin_fminf(zl[2], __int_as_float(f4.z)) - zl[1]);
  local += sig[2] * (__builtin_fminf(zl[3], __int_as_float(f4.w)) - zl[2]);
  float succ3 = lastl ? (zl[3] + sd)
                      : __builtin_fminf(zcn3, __int_as_float(fnn3));
  local += sig[3] * (succ3 - zl[3]);
  // nz side
  local += sgn2[0] * (__builtin_fminf(nzv[1], zrv[0]) - nzv[0]);
  local += sgn2[1] * (__builtin_fminf(nzv[2], zrv[1]) - nzv[1]);
  local += sgn2[2] * (__builtin_fminf(nzv[3], zrv[2]) - nzv[2]);
  float nzn = lastl ? __int_as_float(FLTMAX_I) : nzn3;
  local += sgn2[3] * (__builtin_fminf(nzn, zrv[3]) - nzv[3]);

  float tot = seg32_scan_add(local);    // lane 31/63 holds each ray's total
  if (li == 31) {
    int ray = base + half;
    if (ray < nrays) out[ray] = fexp2(NLOG2E_F * tot);
  }
}

extern "C" void kernel_launch(void* const* d_in, const int* in_sizes, int n_in,
                              void* d_out, int out_size, void* d_ws, size_t ws_size,
                              hipStream_t stream) {
  const float* rays_o = (const float*)d_in[0];
  const float* rays_d = (const float*)d_in[1];
  const float* nearp  = (const float*)d_in[2];
  const float* farp   = (const float*)d_in[3];
  const float* noise  = (const float*)d_in[4];
  const float* W1     = (const float*)d_in[5];
  const float* b1     = (const float*)d_in[6];
  const float* W2     = (const float*)d_in[7];
  const float* b2     = (const float*)d_in[8];
  float* out = (float*)d_out;
  const int nrays = in_sizes[2];
  const int raysPerBlock = WPB * 2;
  const int blocks = (nrays + raysPerBlock - 1) / raysPerBlock;
  nerf_transmittance_kernel<<<blocks, 256, 0, stream>>>(
      rays_o, rays_d, nearp, farp, noise, W1, b1, W2, b2, out, nrays);
}